// Round 1
// baseline (100.567 us; speedup 1.0000x reference)
//
#include <hip/hip_runtime.h>
#include <math.h>

#define D      3
#define HID    64
#define WIDTH  64
#define BATCH  500000
#define BLOCKP (D * WIDTH)          // 192
#define NPAR   (3 * BLOCKP + WIDTH) // 640
#define NCHUNK (BATCH / 4)          // 125000 chunks of 4 elements

__global__ __launch_bounds__(256) void cnf_kernel(
    const float* __restrict__ t,
    const float* __restrict__ z,
    const float* __restrict__ fc1_w, const float* __restrict__ fc1_b,
    const float* __restrict__ fc2_w, const float* __restrict__ fc2_b,
    const float* __restrict__ fc3_w, const float* __restrict__ fc3_b,
    float* __restrict__ out)
{
    __shared__ float p1[HID];
    __shared__ float p2[HID];
    __shared__ float p3[NPAR];
    __shared__ float4 pA[WIDTH];  // {W0, W1, W2, B}
    __shared__ float4 pB[WIDTH];  // {U0, U1, U2, wu}

    const int tid = threadIdx.x;

    // ---------- hypernet (redundant per block; fc3_w lives in L2) ----------
    if (tid < HID) {
        p1[tid] = tanhf(t[0] * fc1_w[tid] + fc1_b[tid]);
    }
    __syncthreads();
    if (tid < HID) {
        float acc = fc2_b[tid];
        const float* wrow = fc2_w + tid * HID;
        #pragma unroll 16
        for (int k = 0; k < HID; ++k) acc += wrow[k] * p1[k];
        p2[tid] = tanhf(acc);
    }
    __syncthreads();
    for (int o = tid; o < NPAR; o += blockDim.x) {
        float acc = fc3_b[o];
        const float4* w4 = (const float4*)(fc3_w + o * HID);
        const float4* q4 = (const float4*)p2;
        #pragma unroll
        for (int k = 0; k < HID / 4; ++k) {
            float4 w = w4[k];
            float4 q = q4[k];
            acc += w.x * q.x + w.y * q.y + w.z * q.z + w.w * q.w;
        }
        p3[o] = acc;
    }
    __syncthreads();
    if (tid < WIDTH) {
        float W0 = p3[3 * tid + 0], W1 = p3[3 * tid + 1], W2 = p3[3 * tid + 2];
        float U0 = p3[BLOCKP + 3 * tid + 0], U1 = p3[BLOCKP + 3 * tid + 1], U2 = p3[BLOCKP + 3 * tid + 2];
        float G0 = p3[2 * BLOCKP + 3 * tid + 0], G1 = p3[2 * BLOCKP + 3 * tid + 1], G2 = p3[2 * BLOCKP + 3 * tid + 2];
        float B  = p3[3 * BLOCKP + tid];
        U0 *= 1.0f / (1.0f + expf(-G0));
        U1 *= 1.0f / (1.0f + expf(-G1));
        U2 *= 1.0f / (1.0f + expf(-G2));
        float wu = W0 * U0 + W1 * U1 + W2 * U2;
        pA[tid] = make_float4(W0, W1, W2, B);
        pB[tid] = make_float4(U0, U1, U2, wu);
    }
    __syncthreads();

    // ---------- main batch loop: one chunk of 4 elements per thread ----------
    const int gtid = blockIdx.x * blockDim.x + tid;
    if (gtid >= NCHUNK) return;

    const float4* z4 = (const float4*)z + (size_t)gtid * 3;
    float4 za = z4[0], zb = z4[1], zc = z4[2];
    // element e components (row-major z[n][3]):
    float z0[4] = {za.x, za.w, zb.z, zc.y};
    float z1[4] = {za.y, zb.x, zb.w, zc.z};
    float z2[4] = {za.z, zb.y, zc.x, zc.w};

    float dz0[4] = {0.f, 0.f, 0.f, 0.f};
    float dz1[4] = {0.f, 0.f, 0.f, 0.f};
    float dz2[4] = {0.f, 0.f, 0.f, 0.f};
    float tr[4]  = {0.f, 0.f, 0.f, 0.f};

    #pragma unroll 4
    for (int j = 0; j < WIDTH; ++j) {
        float4 a = pA[j];   // W0,W1,W2,B   (LDS broadcast, conflict-free)
        float4 b = pB[j];   // U0,U1,U2,wu
        #pragma unroll
        for (int e = 0; e < 4; ++e) {
            float x  = fmaf(z0[e], a.x, fmaf(z1[e], a.y, fmaf(z2[e], a.z, a.w)));
            float ex = __expf(x + x);                    // exp(2x); inf-safe
            float r  = __builtin_amdgcn_rcpf(1.0f + ex); // v_rcp_f32
            float h  = fmaf(-2.0f, r, 1.0f);             // tanh(x)
            float g  = fmaf(-h, h, 1.0f);                // 1 - h^2
            dz0[e] = fmaf(h, b.x, dz0[e]);
            dz1[e] = fmaf(h, b.y, dz1[e]);
            dz2[e] = fmaf(h, b.z, dz2[e]);
            tr[e]  = fmaf(g, b.w, tr[e]);
        }
    }

    const float s = 1.0f / (float)WIDTH;
    float4* o4 = (float4*)out + (size_t)gtid * 3;
    o4[0] = make_float4(dz0[0] * s, dz1[0] * s, dz2[0] * s, dz0[1] * s);
    o4[1] = make_float4(dz1[1] * s, dz2[1] * s, dz0[2] * s, dz1[2] * s);
    o4[2] = make_float4(dz2[2] * s, dz0[3] * s, dz1[3] * s, dz2[3] * s);

    float4* l4 = (float4*)(out + 3 * BATCH);
    l4[gtid] = make_float4(-tr[0] * s, -tr[1] * s, -tr[2] * s, -tr[3] * s);
}

extern "C" void kernel_launch(void* const* d_in, const int* in_sizes, int n_in,
                              void* d_out, int out_size, void* d_ws, size_t ws_size,
                              hipStream_t stream) {
    const float* t     = (const float*)d_in[0];
    const float* z     = (const float*)d_in[1];
    // d_in[2] = logp_z : unused by the reference computation
    const float* fc1_w = (const float*)d_in[3];
    const float* fc1_b = (const float*)d_in[4];
    const float* fc2_w = (const float*)d_in[5];
    const float* fc2_b = (const float*)d_in[6];
    const float* fc3_w = (const float*)d_in[7];
    const float* fc3_b = (const float*)d_in[8];
    float* out = (float*)d_out;

    const int threads = 256;
    const int blocks  = (NCHUNK + threads - 1) / threads;  // 489
    cnf_kernel<<<blocks, threads, 0, stream>>>(
        t, z, fc1_w, fc1_b, fc2_w, fc2_b, fc3_w, fc3_b, out);
}

// Round 2
// 95.796 us; speedup vs baseline: 1.0498x; 1.0498x over previous
//
#include <hip/hip_runtime.h>
#include <math.h>

#define D      3
#define HID    64
#define WIDTH  64
#define BATCH  500000
#define BLOCKP (D * WIDTH)          // 192
#define NPAR   (3 * BLOCKP + WIDTH) // 640
#define NCHUNK (BATCH / 4)          // 125000 chunks of 4 elements

typedef float f2 __attribute__((ext_vector_type(2)));

__device__ __forceinline__ f2 sp(float s) { f2 r; r.x = s; r.y = s; return r; }
__device__ __forceinline__ f2 vfma(f2 a, f2 b, f2 c) {
    return __builtin_elementwise_fma(a, b, c);
}

__global__ __launch_bounds__(256) void cnf_kernel(
    const float* __restrict__ t,
    const float* __restrict__ z,
    const float* __restrict__ fc1_w, const float* __restrict__ fc1_b,
    const float* __restrict__ fc2_w, const float* __restrict__ fc2_b,
    const float* __restrict__ fc3_w, const float* __restrict__ fc3_b,
    float* __restrict__ out)
{
    __shared__ float p1[HID];
    __shared__ float p2[HID];
    __shared__ float p3[NPAR];
    __shared__ float4 pA[WIDTH];  // {W0*c, W1*c, W2*c, B*c}  c = 2*log2(e)
    __shared__ float4 pB[WIDTH];  // {U0, U1, U2, wu}

    const int tid = threadIdx.x;

    // ---------- hypernet (redundant per block; weights live in L2) ----------
    if (tid < HID) {
        p1[tid] = tanhf(t[0] * fc1_w[tid] + fc1_b[tid]);
    }
    __syncthreads();
    if (tid < HID) {
        float acc = fc2_b[tid];
        const float* wrow = fc2_w + tid * HID;
        #pragma unroll 16
        for (int k = 0; k < HID; ++k) acc += wrow[k] * p1[k];
        p2[tid] = tanhf(acc);
    }
    __syncthreads();
    for (int o = tid; o < NPAR; o += blockDim.x) {
        float acc = fc3_b[o];
        const float4* w4 = (const float4*)(fc3_w + o * HID);
        const float4* q4 = (const float4*)p2;
        #pragma unroll
        for (int k = 0; k < HID / 4; ++k) {
            float4 w = w4[k];
            float4 q = q4[k];
            acc += w.x * q.x + w.y * q.y + w.z * q.z + w.w * q.w;
        }
        p3[o] = acc;
    }
    __syncthreads();
    if (tid < WIDTH) {
        float W0 = p3[3 * tid + 0], W1 = p3[3 * tid + 1], W2 = p3[3 * tid + 2];
        float U0 = p3[BLOCKP + 3 * tid + 0], U1 = p3[BLOCKP + 3 * tid + 1], U2 = p3[BLOCKP + 3 * tid + 2];
        float G0 = p3[2 * BLOCKP + 3 * tid + 0], G1 = p3[2 * BLOCKP + 3 * tid + 1], G2 = p3[2 * BLOCKP + 3 * tid + 2];
        float B  = p3[3 * BLOCKP + tid];
        U0 *= 1.0f / (1.0f + expf(-G0));
        U1 *= 1.0f / (1.0f + expf(-G1));
        U2 *= 1.0f / (1.0f + expf(-G2));
        float wu = W0 * U0 + W1 * U1 + W2 * U2;   // from UNSCALED W
        // fold 2*log2(e) into W,B: tanh(x) = 1 - 2/(1 + 2^(c*x))
        const float c = 2.8853900817779268f;
        pA[tid] = make_float4(W0 * c, W1 * c, W2 * c, B * c);
        pB[tid] = make_float4(U0, U1, U2, wu);
    }
    __syncthreads();

    // ---------- main batch loop: one chunk of 4 elements per thread ----------
    const int gtid = blockIdx.x * blockDim.x + tid;
    if (gtid >= NCHUNK) return;

    const float4* z4 = (const float4*)z + (size_t)gtid * 3;
    float4 za = z4[0], zb = z4[1], zc = z4[2];
    // elements e0..e3 (row-major z[n][3]); packed as pairs {e0,e1}, {e2,e3}
    f2 z0p[2], z1p[2], z2p[2];
    z0p[0] = (f2){za.x, za.w}; z0p[1] = (f2){zb.z, zc.y};
    z1p[0] = (f2){za.y, zb.x}; z1p[1] = (f2){zb.w, zc.z};
    z2p[0] = (f2){za.z, zb.y}; z2p[1] = (f2){zc.x, zc.w};

    f2 dz0[2] = {sp(0.f), sp(0.f)};
    f2 dz1[2] = {sp(0.f), sp(0.f)};
    f2 dz2[2] = {sp(0.f), sp(0.f)};
    f2 tr[2]  = {sp(0.f), sp(0.f)};

    #pragma unroll 4
    for (int j = 0; j < WIDTH; ++j) {
        float4 a = pA[j];   // scaled W0,W1,W2,B (LDS broadcast, conflict-free)
        float4 b = pB[j];   // U0,U1,U2,wu
        #pragma unroll
        for (int p = 0; p < 2; ++p) {
            // x' = c * (z . W + B)  -> tanh(x) = 1 - 2 * rcp(1 + exp2(x'))
            f2 x = vfma(z0p[p], sp(a.x),
                    vfma(z1p[p], sp(a.y),
                     vfma(z2p[p], sp(a.z), sp(a.w))));
            float e0 = __builtin_amdgcn_exp2f(x.x);     // v_exp_f32; inf/0-safe
            float e1 = __builtin_amdgcn_exp2f(x.y);
            f2 den = (f2){e0, e1} + sp(1.0f);
            f2 r;
            r.x = __builtin_amdgcn_rcpf(den.x);
            r.y = __builtin_amdgcn_rcpf(den.y);
            f2 h = vfma(sp(-2.0f), r, sp(1.0f));        // tanh
            f2 g = vfma(-h, h, sp(1.0f));               // 1 - h^2
            dz0[p] = vfma(h, sp(b.x), dz0[p]);
            dz1[p] = vfma(h, sp(b.y), dz1[p]);
            dz2[p] = vfma(h, sp(b.z), dz2[p]);
            tr[p]  = vfma(g, sp(b.w), tr[p]);
        }
    }

    const float s = 1.0f / (float)WIDTH;
    float4* o4 = (float4*)out + (size_t)gtid * 3;
    o4[0] = make_float4(dz0[0].x * s, dz1[0].x * s, dz2[0].x * s, dz0[0].y * s);
    o4[1] = make_float4(dz1[0].y * s, dz2[0].y * s, dz0[1].x * s, dz1[1].x * s);
    o4[2] = make_float4(dz2[1].x * s, dz0[1].y * s, dz1[1].y * s, dz2[1].y * s);

    float4* l4 = (float4*)(out + 3 * BATCH);
    l4[gtid] = make_float4(-tr[0].x * s, -tr[0].y * s, -tr[1].x * s, -tr[1].y * s);
}

extern "C" void kernel_launch(void* const* d_in, const int* in_sizes, int n_in,
                              void* d_out, int out_size, void* d_ws, size_t ws_size,
                              hipStream_t stream) {
    const float* t     = (const float*)d_in[0];
    const float* z     = (const float*)d_in[1];
    // d_in[2] = logp_z : unused by the reference computation
    const float* fc1_w = (const float*)d_in[3];
    const float* fc1_b = (const float*)d_in[4];
    const float* fc2_w = (const float*)d_in[5];
    const float* fc2_b = (const float*)d_in[6];
    const float* fc3_w = (const float*)d_in[7];
    const float* fc3_b = (const float*)d_in[8];
    float* out = (float*)d_out;

    const int threads = 256;
    const int blocks  = (NCHUNK + threads - 1) / threads;  // 489
    cnf_kernel<<<blocks, threads, 0, stream>>>(
        t, z, fc1_w, fc1_b, fc2_w, fc2_b, fc3_w, fc3_b, out);
}

// Round 3
// 95.608 us; speedup vs baseline: 1.0519x; 1.0020x over previous
//
#include <hip/hip_runtime.h>
#include <math.h>

#define D      3
#define HID    64
#define WIDTH  64
#define BATCH  500000
#define BLOCKP (D * WIDTH)          // 192
#define NPAR   (3 * BLOCKP + WIDTH) // 640
#define NCHUNK (BATCH / 4)          // 125000 chunks of 4 elements

typedef float f2 __attribute__((ext_vector_type(2)));

__device__ __forceinline__ f2 sp(float s) { f2 r; r.x = s; r.y = s; return r; }
__device__ __forceinline__ f2 vfma(f2 a, f2 b, f2 c) {
    return __builtin_elementwise_fma(a, b, c);
}

__global__ __launch_bounds__(256) void cnf_kernel(
    const float* __restrict__ t,
    const float* __restrict__ z,
    const float* __restrict__ fc1_w, const float* __restrict__ fc1_b,
    const float* __restrict__ fc2_w, const float* __restrict__ fc2_b,
    const float* __restrict__ fc3_w, const float* __restrict__ fc3_b,
    float* __restrict__ out)
{
    __shared__ float p1[HID];
    __shared__ float p2[HID];
    __shared__ float p3[NPAR];
    __shared__ float4 pA[WIDTH];  // {W0*c, W1*c, W2*c, B*c}  c = 2*log2(e)
    __shared__ float4 pB[WIDTH];  // {U0/64, U1/64, U2/64, -wu/64}

    const int tid = threadIdx.x;

    // ---------- hypernet (redundant per block; weights live in L2) ----------
    if (tid < HID) {
        p1[tid] = tanhf(t[0] * fc1_w[tid] + fc1_b[tid]);
    }
    __syncthreads();
    if (tid < HID) {
        // 4 partial accumulators to break the serial FMA dependency chain
        const float* wrow = fc2_w + tid * HID;
        float a0 = 0.f, a1 = 0.f, a2 = 0.f, a3 = 0.f;
        #pragma unroll
        for (int k = 0; k < HID; k += 4) {
            a0 = fmaf(wrow[k + 0], p1[k + 0], a0);
            a1 = fmaf(wrow[k + 1], p1[k + 1], a1);
            a2 = fmaf(wrow[k + 2], p1[k + 2], a2);
            a3 = fmaf(wrow[k + 3], p1[k + 3], a3);
        }
        p2[tid] = tanhf(((a0 + a1) + (a2 + a3)) + fc2_b[tid]);
    }
    __syncthreads();
    for (int o = tid; o < NPAR; o += blockDim.x) {
        float acc = fc3_b[o];
        const float4* w4 = (const float4*)(fc3_w + o * HID);
        const float4* q4 = (const float4*)p2;
        #pragma unroll
        for (int k = 0; k < HID / 4; ++k) {
            float4 w = w4[k];
            float4 q = q4[k];
            acc += w.x * q.x + w.y * q.y + w.z * q.z + w.w * q.w;
        }
        p3[o] = acc;
    }
    __syncthreads();
    if (tid < WIDTH) {
        float W0 = p3[3 * tid + 0], W1 = p3[3 * tid + 1], W2 = p3[3 * tid + 2];
        float U0 = p3[BLOCKP + 3 * tid + 0], U1 = p3[BLOCKP + 3 * tid + 1], U2 = p3[BLOCKP + 3 * tid + 2];
        float G0 = p3[2 * BLOCKP + 3 * tid + 0], G1 = p3[2 * BLOCKP + 3 * tid + 1], G2 = p3[2 * BLOCKP + 3 * tid + 2];
        float B  = p3[3 * BLOCKP + tid];
        U0 *= 1.0f / (1.0f + expf(-G0));
        U1 *= 1.0f / (1.0f + expf(-G1));
        U2 *= 1.0f / (1.0f + expf(-G2));
        float wu = W0 * U0 + W1 * U1 + W2 * U2;   // from UNSCALED W,U
        // fold 2*log2(e) into W,B: tanh(x) = 1 - 2/(1 + 2^(c*x))
        const float c = 2.8853900817779268f;
        const float s = 1.0f / (float)WIDTH;
        pA[tid] = make_float4(W0 * c, W1 * c, W2 * c, B * c);
        pB[tid] = make_float4(U0 * s, U1 * s, U2 * s, -wu * s);
    }
    __syncthreads();

    // ---------- main batch loop: one chunk of 4 elements per thread ----------
    const int gtid = blockIdx.x * blockDim.x + tid;
    if (gtid >= NCHUNK) return;

    const float4* z4 = (const float4*)z + (size_t)gtid * 3;
    float4 za = z4[0], zb = z4[1], zc = z4[2];
    // elements e0..e3 (row-major z[n][3]); packed as pairs {e0,e1}, {e2,e3}
    f2 z0p[2], z1p[2], z2p[2];
    z0p[0] = (f2){za.x, za.w}; z0p[1] = (f2){zb.z, zc.y};
    z1p[0] = (f2){za.y, zb.x}; z1p[1] = (f2){zb.w, zc.z};
    z2p[0] = (f2){za.z, zb.y}; z2p[1] = (f2){zc.x, zc.w};

    f2 dz0[2] = {sp(0.f), sp(0.f)};
    f2 dz1[2] = {sp(0.f), sp(0.f)};
    f2 dz2[2] = {sp(0.f), sp(0.f)};
    f2 tr[2]  = {sp(0.f), sp(0.f)};

    #pragma unroll 4
    for (int j = 0; j < WIDTH; ++j) {
        float4 a = pA[j];   // scaled W0,W1,W2,B (LDS broadcast, conflict-free)
        float4 b = pB[j];   // scaled U0,U1,U2,-wu

        // x' = c*(z.W + B), clamped at 30 (exact: h(30') == 1.0f in fp32,
        // and caps the 4-way product below FLT_MAX)
        f2 xa = vfma(z0p[0], sp(a.x), vfma(z1p[0], sp(a.y), vfma(z2p[0], sp(a.z), sp(a.w))));
        f2 xb = vfma(z0p[1], sp(a.x), vfma(z1p[1], sp(a.y), vfma(z2p[1], sp(a.z), sp(a.w))));
        xa = __builtin_elementwise_min(xa, sp(30.0f));
        xb = __builtin_elementwise_min(xb, sp(30.0f));

        f2 da, db;                                 // d_e = 1 + 2^(x'_e)
        da.x = __builtin_amdgcn_exp2f(xa.x);
        da.y = __builtin_amdgcn_exp2f(xa.y);
        db.x = __builtin_amdgcn_exp2f(xb.x);
        db.y = __builtin_amdgcn_exp2f(xb.y);
        da = da + sp(1.0f);
        db = db + sp(1.0f);

        // Montgomery batch inversion: 1 rcp instead of 4
        f2 q = da * db;                            // {d0*d2, d1*d3}
        float R = __builtin_amdgcn_rcpf(q.x * q.y);
        f2 rq; rq.x = R * q.y; rq.y = R * q.x;     // {1/(d0 d2), 1/(d1 d3)}
        f2 inva = rq * db;                         // {1/d0, 1/d1}
        f2 invb = rq * da;                         // {1/d2, 1/d3}

        f2 ha = vfma(sp(-2.0f), inva, sp(1.0f));   // tanh
        f2 hb = vfma(sp(-2.0f), invb, sp(1.0f));
        f2 ga = vfma(-ha, ha, sp(1.0f));           // 1 - h^2
        f2 gb = vfma(-hb, hb, sp(1.0f));

        dz0[0] = vfma(ha, sp(b.x), dz0[0]);  dz0[1] = vfma(hb, sp(b.x), dz0[1]);
        dz1[0] = vfma(ha, sp(b.y), dz1[0]);  dz1[1] = vfma(hb, sp(b.y), dz1[1]);
        dz2[0] = vfma(ha, sp(b.z), dz2[0]);  dz2[1] = vfma(hb, sp(b.z), dz2[1]);
        tr[0]  = vfma(ga, sp(b.w), tr[0]);   tr[1]  = vfma(gb, sp(b.w), tr[1]);
    }

    // scale (1/64) and trace negation were pre-folded into pB
    float4* o4 = (float4*)out + (size_t)gtid * 3;
    o4[0] = make_float4(dz0[0].x, dz1[0].x, dz2[0].x, dz0[0].y);
    o4[1] = make_float4(dz1[0].y, dz2[0].y, dz0[1].x, dz1[1].x);
    o4[2] = make_float4(dz2[1].x, dz0[1].y, dz1[1].y, dz2[1].y);

    float4* l4 = (float4*)(out + 3 * BATCH);
    l4[gtid] = make_float4(tr[0].x, tr[0].y, tr[1].x, tr[1].y);
}

extern "C" void kernel_launch(void* const* d_in, const int* in_sizes, int n_in,
                              void* d_out, int out_size, void* d_ws, size_t ws_size,
                              hipStream_t stream) {
    const float* t     = (const float*)d_in[0];
    const float* z     = (const float*)d_in[1];
    // d_in[2] = logp_z : unused by the reference computation
    const float* fc1_w = (const float*)d_in[3];
    const float* fc1_b = (const float*)d_in[4];
    const float* fc2_w = (const float*)d_in[5];
    const float* fc2_b = (const float*)d_in[6];
    const float* fc3_w = (const float*)d_in[7];
    const float* fc3_b = (const float*)d_in[8];
    float* out = (float*)d_out;

    const int threads = 256;
    const int blocks  = (NCHUNK + threads - 1) / threads;  // 489
    cnf_kernel<<<blocks, threads, 0, stream>>>(
        t, z, fc1_w, fc1_b, fc2_w, fc2_b, fc3_w, fc3_b, out);
}